// Round 1
// baseline (664.033 us; speedup 1.0000x reference)
//
#include <hip/hip_runtime.h>
#include <stdint.h>

// Problem dims (fixed by the reference setup)
#define MDIM 8192   // batch B
#define NDIM 4096   // OUT
#define KDIM 4096   // IN
#define BM 128
#define BN 128
#define BK 32

typedef __bf16 bf16x8 __attribute__((ext_vector_type(8)));
typedef float f32x4 __attribute__((ext_vector_type(4)));

// fp32 -> bf16 round-to-nearest-even
__device__ __forceinline__ uint16_t f2bf_rne(float f) {
  uint32_t u = __float_as_uint(f);
  u += 0x7fffu + ((u >> 16) & 1u);
  return (uint16_t)(u >> 16);
}

// ---- Kernel 1: x fp32 -> bf16 (8 elems/thread, 32B read / 16B write) ----
__global__ void cvt_x_kernel(const float* __restrict__ x, uint16_t* __restrict__ xb) {
  int t = blockIdx.x * 256 + threadIdx.x;
  const float4* x4 = (const float4*)x;
  float4 a = x4[2 * t];
  float4 b = x4[2 * t + 1];
  union { uint16_t h[8]; uint4 v; } r;
  r.h[0] = f2bf_rne(a.x); r.h[1] = f2bf_rne(a.y);
  r.h[2] = f2bf_rne(a.z); r.h[3] = f2bf_rne(a.w);
  r.h[4] = f2bf_rne(b.x); r.h[5] = f2bf_rne(b.y);
  r.h[6] = f2bf_rne(b.z); r.h[7] = f2bf_rne(b.w);
  ((uint4*)xb)[t] = r.v;
}

// ---- Kernel 2: W -> 12x12-block-symmetrized bf16 ----
// W_sym[o,i] = 0.5*(W[o,i] + W[(o/12)*12 + i%12, (i/12)*12 + o%12]) for o,i < 4092
// ragged strips (>=4092) pass through unchanged.
__global__ void symw_kernel(const float* __restrict__ W, uint16_t* __restrict__ Wb) {
  int o = blockIdx.x;
  int om = o % 12;
  int ob = o - om;           // (o/12)*12
  bool orow = o < 4092;
  for (int i = threadIdx.x; i < KDIM; i += 256) {
    float w = W[o * KDIM + i];
    float v = w;
    if (orow && i < 4092) {
      int im = i % 12;
      int pr = ob + im;        // partner row
      int pc = (i - im) + om;  // partner col
      v = 0.5f * (w + W[pr * KDIM + pc]);
    }
    Wb[o * KDIM + i] = f2bf_rne(v);
  }
}

// ---- Kernel 3: C[m,n] = sum_k A[m,k]*B[n,k] + bias[n]  (A: MxK bf16, B: NxK bf16) ----
// m97 structure: 128x128 tile, BK=32, 4 waves (2x2), each wave 64x64 via 4x4 mfma 16x16x32,
// global_load_lds width=16 staging into unpadded row-major LDS tiles.
__global__ __launch_bounds__(256) void gemm_bt_kernel(
    const uint16_t* __restrict__ A, const uint16_t* __restrict__ B,
    const float* __restrict__ bias, float* __restrict__ C) {
  __shared__ uint16_t As[BM * BK];  // 8 KB, row-major [128][32], NO padding (global_load_lds)
  __shared__ uint16_t Bs[BN * BK];  // 8 KB

  const int tid = threadIdx.x;
  const int wave = tid >> 6;
  const int lane = tid & 63;
  const int lane15 = lane & 15;
  const int quad = lane >> 4;
  const int wm = (wave >> 1) << 6;  // wave's m-offset within tile (0 or 64)
  const int wn = (wave & 1) << 6;   // wave's n-offset within tile (0 or 64)
  const int bm0 = blockIdx.y * BM;
  const int bn0 = blockIdx.x * BN;

  const f32x4 zero = {0.f, 0.f, 0.f, 0.f};
  f32x4 acc[4][4];
#pragma unroll
  for (int i = 0; i < 4; ++i)
#pragma unroll
    for (int j = 0; j < 4; ++j) acc[i][j] = zero;

  // Staging: 128 rows x 64 B = 512 chunks of 16 B; 256 threads -> 2 calls per tile.
  // Chunk c -> row c>>2, 16B-subcol c&3. LDS dest = wave-uniform base + lane*16.
  const int c0 = tid;        // call 0 chunk
  const int c1 = 256 + tid;  // call 1 chunk
  const uint16_t* gA0 = A + (bm0 + (c0 >> 2)) * KDIM + (c0 & 3) * 8;
  const uint16_t* gA1 = A + (bm0 + (c1 >> 2)) * KDIM + (c1 & 3) * 8;
  const uint16_t* gB0 = B + (bn0 + (c0 >> 2)) * KDIM + (c0 & 3) * 8;
  const uint16_t* gB1 = B + (bn0 + (c1 >> 2)) * KDIM + (c1 & 3) * 8;
  uint16_t* lA0 = As + wave * 512;         // bytes: wave*1024
  uint16_t* lA1 = As + 2048 + wave * 512;  // bytes: 4096 + wave*1024
  uint16_t* lB0 = Bs + wave * 512;
  uint16_t* lB1 = Bs + 2048 + wave * 512;

  for (int k0 = 0; k0 < KDIM; k0 += BK) {
    __builtin_amdgcn_global_load_lds(
        (__attribute__((address_space(1))) void*)(gA0 + k0),
        (__attribute__((address_space(3))) void*)lA0, 16, 0, 0);
    __builtin_amdgcn_global_load_lds(
        (__attribute__((address_space(1))) void*)(gA1 + k0),
        (__attribute__((address_space(3))) void*)lA1, 16, 0, 0);
    __builtin_amdgcn_global_load_lds(
        (__attribute__((address_space(1))) void*)(gB0 + k0),
        (__attribute__((address_space(3))) void*)lB0, 16, 0, 0);
    __builtin_amdgcn_global_load_lds(
        (__attribute__((address_space(1))) void*)(gB1 + k0),
        (__attribute__((address_space(3))) void*)lB1, 16, 0, 0);
    __syncthreads();  // compiler emits vmcnt(0) drain before s_barrier

    bf16x8 af[4], bfr[4];
#pragma unroll
    for (int mi = 0; mi < 4; ++mi)
      af[mi] = *(const bf16x8*)(As + (wm + mi * 16 + lane15) * BK + quad * 8);
#pragma unroll
    for (int ni = 0; ni < 4; ++ni)
      bfr[ni] = *(const bf16x8*)(Bs + (wn + ni * 16 + lane15) * BK + quad * 8);

#pragma unroll
    for (int mi = 0; mi < 4; ++mi)
#pragma unroll
      for (int ni = 0; ni < 4; ++ni)
        acc[mi][ni] = __builtin_amdgcn_mfma_f32_16x16x32_bf16(af[mi], bfr[ni], acc[mi][ni], 0, 0, 0);
    __syncthreads();  // protect LDS from next iteration's staging
  }

  // Epilogue: C/D layout col=lane&15, row=quad*4+reg  [verified m89/m91]
#pragma unroll
  for (int ni = 0; ni < 4; ++ni) {
    const int n = bn0 + wn + ni * 16 + lane15;
    const float bv = bias[n];
#pragma unroll
    for (int mi = 0; mi < 4; ++mi) {
      const int mrow = bm0 + wm + mi * 16 + quad * 4;
#pragma unroll
      for (int r = 0; r < 4; ++r)
        C[(mrow + r) * NDIM + n] = acc[mi][ni][r] + bv;
    }
  }
}

extern "C" void kernel_launch(void* const* d_in, const int* in_sizes, int n_in,
                              void* d_out, int out_size, void* d_ws, size_t ws_size,
                              hipStream_t stream) {
  const float* x    = (const float*)d_in[0];  // (8192, 4096) fp32
  const float* W    = (const float*)d_in[1];  // (4096, 4096) fp32
  const float* bias = (const float*)d_in[2];  // (4096,) fp32
  float* out = (float*)d_out;                 // (8192, 4096) fp32

  // Workspace layout: x_bf16 (64 MiB) | W_sym_bf16 (32 MiB) = 96 MiB total
  uint16_t* xb = (uint16_t*)d_ws;
  uint16_t* wb = xb + (size_t)MDIM * KDIM;

  cvt_x_kernel<<<(MDIM * KDIM) / (8 * 256), 256, 0, stream>>>(x, xb);
  symw_kernel<<<NDIM, 256, 0, stream>>>(W, wb);

  dim3 grid(NDIM / BN, MDIM / BM);  // (32, 64) = 2048 blocks
  gemm_bt_kernel<<<grid, 256, 0, stream>>>(xb, wb, bias, out);
}